// Round 7
// baseline (184.504 us; speedup 1.0000x reference)
//
#include <hip/hip_runtime.h>
#include <hip/hip_bf16.h>

typedef __attribute__((ext_vector_type(8))) __bf16 bf16x8;
typedef __attribute__((ext_vector_type(2))) __bf16 bf16x2;
typedef __attribute__((ext_vector_type(4))) float floatx4;
typedef __attribute__((ext_vector_type(4))) unsigned short us4;
typedef __attribute__((ext_vector_type(8))) unsigned short us8;
typedef __attribute__((ext_vector_type(4))) short s16x4;
typedef __attribute__((ext_vector_type(2))) unsigned int uint2v;
typedef __attribute__((ext_vector_type(4))) unsigned int uint4v;

#define MFMA16(A, B, C) __builtin_amdgcn_mfma_f32_16x16x32_bf16((A), (B), (C), 0, 0, 0)
#define MFMA1K(A, B, C) __builtin_amdgcn_mfma_f32_16x16x16bf16_1k((A), (B), (C), 0, 0, 0)

#define LOG2E 1.44269504088896340736f

#if __has_builtin(__builtin_amdgcn_exp2f)
#define EXP2F(x) __builtin_amdgcn_exp2f(x)
#else
#define EXP2F(x) exp2f(x)
#endif

static __device__ __forceinline__ unsigned short f2bfbits(float f) {
    __hip_bfloat16 h = __float2bfloat16(f);
    union { __hip_bfloat16 h; unsigned short u; } cv;
    cv.h = h;
    return cv.u;
}
// fast bf16 RNE (finite moderate values only)
static __device__ __forceinline__ unsigned int rne32(float f) {
    unsigned int u = __builtin_bit_cast(unsigned int, f);
    return u + 0x7fffu + ((u >> 16) & 1u);
}
static __device__ __forceinline__ unsigned short rne16(float f) {
    return (unsigned short)(rne32(f) >> 16);
}

#if __has_builtin(__builtin_amdgcn_cvt_pk_bf16_f32)
static __device__ __forceinline__ s16x4 pack4(float e0, float e1, float e2, float e3) {
    bf16x2 lo = __builtin_amdgcn_cvt_pk_bf16_f32(e0, e1);
    bf16x2 hi = __builtin_amdgcn_cvt_pk_bf16_f32(e2, e3);
    uint2v u = {__builtin_bit_cast(unsigned int, lo), __builtin_bit_cast(unsigned int, hi)};
    return __builtin_bit_cast(s16x4, u);
}
static __device__ __forceinline__ bf16x8 cvt8(floatx4 a, floatx4 b) {
    bf16x2 p0 = __builtin_amdgcn_cvt_pk_bf16_f32(a[0], a[1]);
    bf16x2 p1 = __builtin_amdgcn_cvt_pk_bf16_f32(a[2], a[3]);
    bf16x2 p2 = __builtin_amdgcn_cvt_pk_bf16_f32(b[0], b[1]);
    bf16x2 p3 = __builtin_amdgcn_cvt_pk_bf16_f32(b[2], b[3]);
    uint4v u = {__builtin_bit_cast(unsigned int, p0), __builtin_bit_cast(unsigned int, p1),
                __builtin_bit_cast(unsigned int, p2), __builtin_bit_cast(unsigned int, p3)};
    return __builtin_bit_cast(bf16x8, u);
}
#else
static __device__ __forceinline__ s16x4 pack4(float e0, float e1, float e2, float e3) {
    unsigned int pa = __builtin_amdgcn_perm(rne32(e1), rne32(e0), 0x07060302u);
    unsigned int pb = __builtin_amdgcn_perm(rne32(e3), rne32(e2), 0x07060302u);
    uint2v u = {pa, pb};
    return __builtin_bit_cast(s16x4, u);
}
static __device__ __forceinline__ bf16x8 cvt8(floatx4 a, floatx4 b) {
    us8 u;
#pragma unroll
    for (int i = 0; i < 4; i++) { u[i] = rne16(a[i]); u[4 + i] = rne16(b[i]); }
    return __builtin_bit_cast(bf16x8, u);
}
#endif

static __device__ __forceinline__ bf16x8 load_bf8(const __hip_bfloat16* p) {
    return *reinterpret_cast<const bf16x8*>(p);
}
static __device__ __forceinline__ float bf2f(unsigned short u) {
    unsigned int w = ((unsigned int)u) << 16;
    return __builtin_bit_cast(float, w);
}

// async global->LDS, 16B per lane; lds dest must be wave-uniform base.
static __device__ __forceinline__ void gld16(const void* g, void* l) {
    __builtin_amdgcn_global_load_lds(
        (const __attribute__((address_space(1))) unsigned int*)g,
        (__attribute__((address_space(3))) unsigned int*)l, 16, 0, 0);
}

// Fragment layouts (16-row tile = 1024 bf16):
//   qf/kf[tile][h(2)][lane(64)][e(8)]: M[tile*16 + (lane&15)][h*32 + (lane>>4)*8 + e]
//   vf[tile][t(4)][lane(64)][e(4)]:  V[tile*16 + (lane>>4)*4 + e][t*16 + (lane&15)]
//   rl[row] = 1/sum_j exp2(s'_row,j)  (f32, 16384 entries)
// K is pre-scaled by log2(e) (weights+bias) so exp(s) == exp2(s').

// ---------------------------------------------------------------------------
// K1: QKV projection with fused weight prep (unchanged from R5/R6).
// ---------------------------------------------------------------------------
__global__ __launch_bounds__(256) void proj_qkv(
    const float* __restrict__ x,
    const float* __restrict__ dwq, const float* __restrict__ pwq,
    const float* __restrict__ dwk, const float* __restrict__ pwk,
    const float* __restrict__ dwv, const float* __restrict__ pwv,
    const float* __restrict__ bqp, const float* __restrict__ bkp,
    const float* __restrict__ bvp,
    __hip_bfloat16* __restrict__ qf, __hip_bfloat16* __restrict__ kf,
    __hip_bfloat16* __restrict__ vf)
{
    __shared__ __hip_bfloat16 wle[16384];   // 32 KB panel [d=64][c=256]
    int b = blockIdx.x;          // 768 blocks
    int p = b >> 8;              // 0=q 1=k 2=v
    int tg = b & 255;
    int tid = threadIdx.x;

    const float* dw = (p == 0) ? dwq : ((p == 1) ? dwk : dwv);
    const float* pw = (p == 0) ? pwq : ((p == 1) ? pwk : pwv);
    float scale = (p == 1) ? LOG2E : 1.0f;

    {
        float dwc = dw[tid];     // c = tid for every fill iteration
#pragma unroll
        for (int k = 0; k < 64; k++) {
            int idx = (k * 256 + tid) ^ ((k & 7) << 3);
            wle[idx] = __float2bfloat16(dwc * pw[tid * 64 + k] * scale);
        }
    }
    __syncthreads();

    int wv = tid >> 6;
    int wid = tg * 4 + wv;       // tile 0..1023
    int lane = tid & 63;
    int l15 = lane & 15, quad = lane >> 4;

    floatx4 acc[4];
#pragma unroll
    for (int t = 0; t < 4; t++) acc[t] = (floatx4){0.f, 0.f, 0.f, 0.f};

    const float* xrow = x + (wid * 16 + l15) * 256 + quad * 8;
#pragma unroll
    for (int ks = 0; ks < 8; ks++) {
        floatx4 xa = *reinterpret_cast<const floatx4*>(xrow + ks * 32);
        floatx4 xb = *reinterpret_cast<const floatx4*>(xrow + ks * 32 + 4);
        bf16x8 a = cvt8(xa, xb);
#pragma unroll
        for (int t = 0; t < 4; t++) {
            int j0 = ((t * 16 + l15) * 256 + ks * 32 + quad * 8) ^ ((l15 & 7) << 3);
            bf16x8 bfr = *reinterpret_cast<const bf16x8*>(&wle[j0]);
            acc[t] = MFMA16(a, bfr, acc[t]);
        }
    }
    if (p < 2) {
        __hip_bfloat16* dst = (p == 0) ? qf : kf;
        const float* bias = (p == 0) ? bqp : bkp;
        float bscale = (p == 1) ? LOG2E : 1.0f;
#pragma unroll
        for (int t = 0; t < 4; t++) {
            float bsv = bias[t * 16 + l15] * bscale;
            int off0 = wid * 1024 + (t >> 1) * 512 +
                       (((((t & 1) << 1) | (l15 >> 3)) * 16 + quad * 4) * 8) + (l15 & 7);
#pragma unroll
            for (int r = 0; r < 4; r++)
                dst[off0 + r * 8] = __float2bfloat16(acc[t][r] + bsv);
        }
    } else {
#pragma unroll
        for (int t = 0; t < 4; t++) {
            float bsv = bvp[t * 16 + l15];
            us4 pk;
#pragma unroll
            for (int r = 0; r < 4; r++) pk[r] = f2bfbits(acc[t][r] + bsv);
            *reinterpret_cast<us4*>(vf + (wid * 4 + t) * 256 + lane * 4) = pk;
        }
    }
}

// ---------------------------------------------------------------------------
// K2: row-sum reciprocals only. 256 blocks x 256 thr; block = 4 i-tiles
// (halves redundant Q traffic vs 2-tile blocks: 262->131 MB), 4 waves split
// j (64 j-tiles each), depth-2 pipeline, 16 MFMA + 32 exp per 4 loads.
// Output: rl[row] = 1/sum. No V scaling pass (pass2 scales P by rl).
// ---------------------------------------------------------------------------
#define P1STEP(B0, B1, B2, B3) do {                                        \
    floatx4 z = (floatx4){0.f, 0.f, 0.f, 0.f};                             \
    floatx4 s0 = MFMA16(a1, (B1), MFMA16(a0, (B0), z));                    \
    floatx4 s1 = MFMA16(a1, (B3), MFMA16(a0, (B2), z));                    \
    floatx4 s2 = MFMA16(a3, (B1), MFMA16(a2, (B0), z));                    \
    floatx4 s3 = MFMA16(a3, (B3), MFMA16(a2, (B2), z));                    \
    floatx4 s4 = MFMA16(a5, (B1), MFMA16(a4, (B0), z));                    \
    floatx4 s5 = MFMA16(a5, (B3), MFMA16(a4, (B2), z));                    \
    floatx4 s6 = MFMA16(a7, (B1), MFMA16(a6, (B0), z));                    \
    floatx4 s7 = MFMA16(a7, (B3), MFMA16(a6, (B2), z));                    \
    _Pragma("unroll")                                                      \
    for (int r = 0; r < 4; r++) {                                          \
        ls0[r] += EXP2F(s0[r]) + EXP2F(s1[r]);                             \
        ls1[r] += EXP2F(s2[r]) + EXP2F(s3[r]);                             \
        ls2[r] += EXP2F(s4[r]) + EXP2F(s5[r]);                             \
        ls3[r] += EXP2F(s6[r]) + EXP2F(s7[r]);                             \
    }                                                                      \
} while (0)

__global__ __launch_bounds__(256) void pass1_rl(
    const __hip_bfloat16* __restrict__ qf, const __hip_bfloat16* __restrict__ kf,
    float* __restrict__ rl)
{
    int itg0 = blockIdx.x * 4;            // i-tiles itg0..itg0+3 (same n)
    int n = itg0 >> 8;
    int jw = threadIdx.x >> 6;            // 0..3
    int lane = threadIdx.x & 63;
    int l15 = lane & 15, quad = lane >> 4;

    const __hip_bfloat16* kp = kf + itg0 * 1024 + lane * 8;
    bf16x8 a0 = load_bf8(kp);
    bf16x8 a1 = load_bf8(kp + 512);
    bf16x8 a2 = load_bf8(kp + 1024);
    bf16x8 a3 = load_bf8(kp + 1536);
    bf16x8 a4 = load_bf8(kp + 2048);
    bf16x8 a5 = load_bf8(kp + 2560);
    bf16x8 a6 = load_bf8(kp + 3072);
    bf16x8 a7 = load_bf8(kp + 3584);

    floatx4 ls0 = (floatx4){0.f, 0.f, 0.f, 0.f};
    floatx4 ls1 = (floatx4){0.f, 0.f, 0.f, 0.f};
    floatx4 ls2 = (floatx4){0.f, 0.f, 0.f, 0.f};
    floatx4 ls3 = (floatx4){0.f, 0.f, 0.f, 0.f};
    const __hip_bfloat16* qp0 = qf + (n * 256 + jw * 64) * 1024 + lane * 8;

    // stage 0 = j-tiles {2i,2i+1}, stage 1 = {2i+2,2i+3}
    bf16x8 s0b0 = load_bf8(qp0);
    bf16x8 s0b1 = load_bf8(qp0 + 512);
    bf16x8 s0b2 = load_bf8(qp0 + 1024);
    bf16x8 s0b3 = load_bf8(qp0 + 1536);
    bf16x8 s1b0 = load_bf8(qp0 + 2048);
    bf16x8 s1b1 = load_bf8(qp0 + 2560);
    bf16x8 s1b2 = load_bf8(qp0 + 3072);
    bf16x8 s1b3 = load_bf8(qp0 + 3584);

    for (int it = 0; it < 32; it += 2) {
        bf16x8 n0 = load_bf8(qp0 + 4096);
        bf16x8 n1 = load_bf8(qp0 + 4608);
        bf16x8 n2 = load_bf8(qp0 + 5120);
        bf16x8 n3 = load_bf8(qp0 + 5632);
        P1STEP(s0b0, s0b1, s0b2, s0b3);
        s0b0 = n0; s0b1 = n1; s0b2 = n2; s0b3 = n3;
        bf16x8 m0 = load_bf8(qp0 + 6144);
        bf16x8 m1 = load_bf8(qp0 + 6656);
        bf16x8 m2 = load_bf8(qp0 + 7168);
        bf16x8 m3 = load_bf8(qp0 + 7680);
        P1STEP(s1b0, s1b1, s1b2, s1b3);
        s1b0 = m0; s1b1 = m1; s1b2 = m2; s1b3 = m3;
        qp0 += 4096;
    }
#pragma unroll
    for (int m = 1; m < 16; m <<= 1) {
#pragma unroll
        for (int r = 0; r < 4; r++) {
            ls0[r] += __shfl_xor(ls0[r], m, 64);
            ls1[r] += __shfl_xor(ls1[r], m, 64);
            ls2[r] += __shfl_xor(ls2[r], m, 64);
            ls3[r] += __shfl_xor(ls3[r], m, 64);
        }
    }
    __shared__ float red[4][64];
    if (l15 == 0) {
#pragma unroll
        for (int r = 0; r < 4; r++) {
            red[jw][quad * 4 + r]      = ls0[r];
            red[jw][16 + quad * 4 + r] = ls1[r];
            red[jw][32 + quad * 4 + r] = ls2[r];
            red[jw][48 + quad * 4 + r] = ls3[r];
        }
    }
    __syncthreads();
    if (threadIdx.x < 64) {
        float tot = red[0][threadIdx.x] + red[1][threadIdx.x] +
                    red[2][threadIdx.x] + red[3][threadIdx.x];
        rl[itg0 * 16 + threadIdx.x] = 1.0f / tot;
    }
}

// ---------------------------------------------------------------------------
// K3: attT partials. LDS-staged K/V shared by 8 waves (R6 win), now staging
// RAW vf + per-block rl (2 KB); P scaled by rl_i before bf16 pack (16 v_mul
// per step, full-rate) -- removes the vfs write/read pass entirely.
// Grid = n(4) x jgrp(8) x ih(8) = 256 blocks x 512 thr, wave = 4 j-tiles.
// ---------------------------------------------------------------------------
#define P2STEP(KA, KB, V0, V1, V2, V3, RLQ) do {                               \
    floatx4 z = (floatx4){0.f, 0.f, 0.f, 0.f};                                 \
    floatx4 s0 = MFMA16((KB), bq0b, MFMA16((KA), bq0a, z));                    \
    floatx4 s1 = MFMA16((KB), bq1b, MFMA16((KA), bq1a, z));                    \
    floatx4 s2 = MFMA16((KB), bq2b, MFMA16((KA), bq2a, z));                    \
    floatx4 s3 = MFMA16((KB), bq3b, MFMA16((KA), bq3a, z));                    \
    s16x4 p0 = pack4(EXP2F(s0[0]) * (RLQ)[0], EXP2F(s0[1]) * (RLQ)[1],         \
                     EXP2F(s0[2]) * (RLQ)[2], EXP2F(s0[3]) * (RLQ)[3]);        \
    s16x4 p1 = pack4(EXP2F(s1[0]) * (RLQ)[0], EXP2F(s1[1]) * (RLQ)[1],         \
                     EXP2F(s1[2]) * (RLQ)[2], EXP2F(s1[3]) * (RLQ)[3]);        \
    s16x4 p2 = pack4(EXP2F(s2[0]) * (RLQ)[0], EXP2F(s2[1]) * (RLQ)[1],         \
                     EXP2F(s2[2]) * (RLQ)[2], EXP2F(s2[3]) * (RLQ)[3]);        \
    s16x4 p3 = pack4(EXP2F(s3[0]) * (RLQ)[0], EXP2F(s3[1]) * (RLQ)[1],         \
                     EXP2F(s3[2]) * (RLQ)[2], EXP2F(s3[3]) * (RLQ)[3]);        \
    acc0[0] = MFMA1K(p0, (V0), acc0[0]);                                       \
    acc1[0] = MFMA1K(p1, (V0), acc1[0]);                                       \
    acc2[0] = MFMA1K(p2, (V0), acc2[0]);                                       \
    acc3[0] = MFMA1K(p3, (V0), acc3[0]);                                       \
    acc0[1] = MFMA1K(p0, (V1), acc0[1]);                                       \
    acc1[1] = MFMA1K(p1, (V1), acc1[1]);                                       \
    acc2[1] = MFMA1K(p2, (V1), acc2[1]);                                       \
    acc3[1] = MFMA1K(p3, (V1), acc3[1]);                                       \
    acc0[2] = MFMA1K(p0, (V2), acc0[2]);                                       \
    acc1[2] = MFMA1K(p1, (V2), acc1[2]);                                       \
    acc2[2] = MFMA1K(p2, (V2), acc2[2]);                                       \
    acc3[2] = MFMA1K(p3, (V2), acc3[2]);                                       \
    acc0[3] = MFMA1K(p0, (V3), acc0[3]);                                       \
    acc1[3] = MFMA1K(p1, (V3), acc1[3]);                                       \
    acc2[3] = MFMA1K(p2, (V3), acc2[3]);                                       \
    acc3[3] = MFMA1K(p3, (V3), acc3[3]);                                       \
} while (0)

__global__ __launch_bounds__(512) void pass2_att(
    const __hip_bfloat16* __restrict__ qf, const __hip_bfloat16* __restrict__ kf,
    const __hip_bfloat16* __restrict__ vf, const float* __restrict__ rl,
    unsigned short* __restrict__ attp)
{
    // double-buffered K/V: per buffer [K(t0) 2KB | K(t1) 2KB | V(t0) 2KB | V(t1) 2KB]
    __shared__ char ldsbuf[2][8192];
    __shared__ float rl_lds[512];
    int b = blockIdx.x;          // 256
    int ih = b & 7;
    int jgrp = (b >> 3) & 7;
    int n = b >> 6;
    int tid = threadIdx.x;
    int w = tid >> 6;            // 0..7
    int lane = tid & 63;
    int l15 = lane & 15, quad = lane >> 4;
    int jt0 = jgrp * 32 + w * 4; // local j-tiles jt0..jt0+3

    int it0 = n * 256 + ih * 32;

    // stage rl for the block's 512 i-rows (2 KB)
    if (tid < 128)
        *reinterpret_cast<floatx4*>(&rl_lds[tid * 4]) =
            *reinterpret_cast<const floatx4*>(&rl[it0 * 16 + tid * 4]);

    const __hip_bfloat16* qp = qf + (n * 256 + jt0) * 1024 + lane * 8;
    bf16x8 bq0a = load_bf8(qp);
    bf16x8 bq0b = load_bf8(qp + 512);
    bf16x8 bq1a = load_bf8(qp + 1024);
    bf16x8 bq1b = load_bf8(qp + 1536);
    bf16x8 bq2a = load_bf8(qp + 2048);
    bf16x8 bq2b = load_bf8(qp + 2560);
    bf16x8 bq3a = load_bf8(qp + 3072);
    bf16x8 bq3b = load_bf8(qp + 3584);

    floatx4 acc0[4], acc1[4], acc2[4], acc3[4];
#pragma unroll
    for (int t = 0; t < 4; t++) {
        acc0[t] = (floatx4){0.f, 0.f, 0.f, 0.f};
        acc1[t] = (floatx4){0.f, 0.f, 0.f, 0.f};
        acc2[t] = (floatx4){0.f, 0.f, 0.f, 0.f};
        acc3[t] = (floatx4){0.f, 0.f, 0.f, 0.f};
    }

    // staging role of this wave: w<4 -> K halves, w>=4 -> V halves
    const char* gbase = (w < 4) ? (const char*)(kf + it0 * 1024)
                                : (const char*)(vf + it0 * 1024);
    const char* gw = gbase + ((w >> 1) & 1) * 2048 + (w & 1) * 1024 + lane * 16;
    char* lw0 = &ldsbuf[0][w * 1024];
    char* lw1 = &ldsbuf[1][w * 1024];

    // prologue: stage phase 0 (tiles 0,1) into buf 0
    gld16(gw, lw0);
    __syncthreads();

    int cur = 0;
    for (int ph = 0; ph < 16; ph++) {
        if (ph < 15)
            gld16(gw + (ph + 1) * 4096, cur ? lw0 : lw1);
        const char* base = ldsbuf[cur];
#pragma unroll
        for (int t = 0; t < 2; t++) {
            bf16x8 a0 = *reinterpret_cast<const bf16x8*>(base + t * 2048 + lane * 16);
            bf16x8 a1 = *reinterpret_cast<const bf16x8*>(base + t * 2048 + 1024 + lane * 16);
            const char* vb = base + 4096 + t * 2048 + lane * 8;
            s16x4 v0 = *reinterpret_cast<const s16x4*>(vb);
            s16x4 v1 = *reinterpret_cast<const s16x4*>(vb + 512);
            s16x4 v2 = *reinterpret_cast<const s16x4*>(vb + 1024);
            s16x4 v3 = *reinterpret_cast<const s16x4*>(vb + 1536);
            floatx4 rlq = *reinterpret_cast<const floatx4*>(
                &rl_lds[(ph * 2 + t) * 16 + quad * 4]);
            P2STEP(a0, a1, v0, v1, v2, v3, rlq);
        }
        __syncthreads();   // drains staging vmcnt + all reads of buf done
        cur ^= 1;
    }
    unsigned short* op0 = attp + ih * 1048576;
#pragma unroll
    for (int t = 0; t < 4; t++) {
        s16x4 k0 = pack4(acc0[t][0], acc0[t][1], acc0[t][2], acc0[t][3]);
        s16x4 k1 = pack4(acc1[t][0], acc1[t][1], acc1[t][2], acc1[t][3]);
        s16x4 k2 = pack4(acc2[t][0], acc2[t][1], acc2[t][2], acc2[t][3]);
        s16x4 k3 = pack4(acc3[t][0], acc3[t][1], acc3[t][2], acc3[t][3]);
        unsigned short* op = op0 + (n * 64 + t * 16 + l15) * 4096 + jt0 * 16 + quad * 4;
        *reinterpret_cast<s16x4*>(op) = k0;
        *reinterpret_cast<s16x4*>(op + 16) = k1;
        *reinterpret_cast<s16x4*>(op + 32) = k2;
        *reinterpret_cast<s16x4*>(op + 48) = k3;
    }
}

// ---------------------------------------------------------------------------
// K4: final sepconv + residual, summing NPART bf16 i-partials.
// Partial reduction uses paired dword loads (2 jj per thread).
// ---------------------------------------------------------------------------
template<int NPART>
__global__ __launch_bounds__(256) void final_out(
    const unsigned short* __restrict__ attp, const float* __restrict__ gco,
    const float* __restrict__ dwa, const float* __restrict__ pwa,
    const float* __restrict__ ba, float* __restrict__ out)
{
    int b = blockIdx.x;       // 2048 blocks
    int n = b >> 9;
    int hh = (b >> 3) & 63;
    int w0 = (b & 7) << 3;
    __shared__ float g[512];
    int tid = threadIdx.x;
    const unsigned short* ap = attp + (n * 64 + hh) * 4096 + w0 * 64;
    {
        int jj0 = tid * 2;    // 256 threads x 2 = 512
        float v0 = 0.f, v1 = 0.f;
#pragma unroll
        for (int ph = 0; ph < NPART; ph++) {
            unsigned int u = *reinterpret_cast<const unsigned int*>(ap + ph * 1048576 + jj0);
            v0 += bf2f((unsigned short)(u & 0xffffu));
            v1 += bf2f((unsigned short)(u >> 16));
        }
        g[jj0] = v0 * dwa[jj0 & 63];
        g[jj0 + 1] = v1 * dwa[(jj0 + 1) & 63];
    }
    __syncthreads();
    float acc[8];
#pragma unroll
    for (int w = 0; w < 8; w++) acc[w] = 0.f;
    for (int cc = 0; cc < 64; cc++) {
        float p = pwa[cc * 256 + tid];
#pragma unroll
        for (int w = 0; w < 8; w++) acc[w] += g[w * 64 + cc] * p;
    }
    float bb = ba[tid];
#pragma unroll
    for (int w = 0; w < 8; w++) {
        int pos = (n * 64 + hh) * 64 + w0 + w;
        float gv = gco[pos * 256 + tid];
        out[pos * 256 + tid] = gv * (acc[w] + bb) + gv;
    }
}

// ---------------------------------------------------------------------------
extern "C" void kernel_launch(void* const* d_in, const int* in_sizes, int n_in,
                              void* d_out, int out_size, void* d_ws, size_t ws_size,
                              hipStream_t stream) {
    const float* x   = (const float*)d_in[0];
    const float* gco = (const float*)d_in[1];
    const float* dwq = (const float*)d_in[2];
    const float* pwq = (const float*)d_in[3];
    const float* bq  = (const float*)d_in[4];
    const float* dwk = (const float*)d_in[5];
    const float* pwk = (const float*)d_in[6];
    const float* bk  = (const float*)d_in[7];
    const float* dwv = (const float*)d_in[8];
    const float* pwv = (const float*)d_in[9];
    const float* bv  = (const float*)d_in[10];
    const float* dwa = (const float*)d_in[11];
    const float* pwa = (const float*)d_in[12];
    const float* ba  = (const float*)d_in[13];
    float* out = (float*)d_out;

    char* ws = (char*)d_ws;
    __hip_bfloat16* qf  = (__hip_bfloat16*)(ws + 98304);          // 2 MB
    __hip_bfloat16* kf  = (__hip_bfloat16*)(ws + 2195456);        // 2 MB
    __hip_bfloat16* vf  = (__hip_bfloat16*)(ws + 4292608);        // 2 MB
    float*          rlb = (float*)(ws + 6389760);                 // 64 KB
    unsigned short* attp = (unsigned short*)(ws + 8486912);       // 8 x 2 MB bf16

    proj_qkv<<<768, 256, 0, stream>>>(x, dwq, pwq, dwk, pwk, dwv, pwv,
                                      bq, bk, bv, qf, kf, vf);
    pass1_rl<<<256, 256, 0, stream>>>(qf, kf, rlb);
    pass2_att<<<256, 512, 0, stream>>>(qf, kf, vf, rlb, attp);
    final_out<8><<<2048, 256, 0, stream>>>(attp, gco, dwa, pwa, ba, out);
}

// Round 8
// 167.237 us; speedup vs baseline: 1.1032x; 1.1032x over previous
//
#include <hip/hip_runtime.h>
#include <hip/hip_bf16.h>

typedef __attribute__((ext_vector_type(8))) __bf16 bf16x8;
typedef __attribute__((ext_vector_type(2))) __bf16 bf16x2;
typedef __attribute__((ext_vector_type(4))) float floatx4;
typedef __attribute__((ext_vector_type(4))) unsigned short us4;
typedef __attribute__((ext_vector_type(8))) unsigned short us8;
typedef __attribute__((ext_vector_type(4))) short s16x4;
typedef __attribute__((ext_vector_type(2))) unsigned int uint2v;
typedef __attribute__((ext_vector_type(4))) unsigned int uint4v;

#define MFMA16(A, B, C) __builtin_amdgcn_mfma_f32_16x16x32_bf16((A), (B), (C), 0, 0, 0)
#define MFMA1K(A, B, C) __builtin_amdgcn_mfma_f32_16x16x16bf16_1k((A), (B), (C), 0, 0, 0)

#define LOG2E 1.44269504088896340736f

#if __has_builtin(__builtin_amdgcn_exp2f)
#define EXP2F(x) __builtin_amdgcn_exp2f(x)
#else
#define EXP2F(x) exp2f(x)
#endif

static __device__ __forceinline__ unsigned short f2bfbits(float f) {
    __hip_bfloat16 h = __float2bfloat16(f);
    union { __hip_bfloat16 h; unsigned short u; } cv;
    cv.h = h;
    return cv.u;
}
// fast bf16 RNE (finite moderate values only)
static __device__ __forceinline__ unsigned int rne32(float f) {
    unsigned int u = __builtin_bit_cast(unsigned int, f);
    return u + 0x7fffu + ((u >> 16) & 1u);
}
static __device__ __forceinline__ unsigned short rne16(float f) {
    return (unsigned short)(rne32(f) >> 16);
}

#if __has_builtin(__builtin_amdgcn_cvt_pk_bf16_f32)
static __device__ __forceinline__ s16x4 pack4(float e0, float e1, float e2, float e3) {
    bf16x2 lo = __builtin_amdgcn_cvt_pk_bf16_f32(e0, e1);
    bf16x2 hi = __builtin_amdgcn_cvt_pk_bf16_f32(e2, e3);
    uint2v u = {__builtin_bit_cast(unsigned int, lo), __builtin_bit_cast(unsigned int, hi)};
    return __builtin_bit_cast(s16x4, u);
}
static __device__ __forceinline__ bf16x8 cvt8(floatx4 a, floatx4 b) {
    bf16x2 p0 = __builtin_amdgcn_cvt_pk_bf16_f32(a[0], a[1]);
    bf16x2 p1 = __builtin_amdgcn_cvt_pk_bf16_f32(a[2], a[3]);
    bf16x2 p2 = __builtin_amdgcn_cvt_pk_bf16_f32(b[0], b[1]);
    bf16x2 p3 = __builtin_amdgcn_cvt_pk_bf16_f32(b[2], b[3]);
    uint4v u = {__builtin_bit_cast(unsigned int, p0), __builtin_bit_cast(unsigned int, p1),
                __builtin_bit_cast(unsigned int, p2), __builtin_bit_cast(unsigned int, p3)};
    return __builtin_bit_cast(bf16x8, u);
}
#else
static __device__ __forceinline__ s16x4 pack4(float e0, float e1, float e2, float e3) {
    unsigned int pa = __builtin_amdgcn_perm(rne32(e1), rne32(e0), 0x07060302u);
    unsigned int pb = __builtin_amdgcn_perm(rne32(e3), rne32(e2), 0x07060302u);
    uint2v u = {pa, pb};
    return __builtin_bit_cast(s16x4, u);
}
static __device__ __forceinline__ bf16x8 cvt8(floatx4 a, floatx4 b) {
    us8 u;
#pragma unroll
    for (int i = 0; i < 4; i++) { u[i] = rne16(a[i]); u[4 + i] = rne16(b[i]); }
    return __builtin_bit_cast(bf16x8, u);
}
#endif

static __device__ __forceinline__ bf16x8 load_bf8(const __hip_bfloat16* p) {
    return *reinterpret_cast<const bf16x8*>(p);
}
static __device__ __forceinline__ float bf2f(unsigned short u) {
    unsigned int w = ((unsigned int)u) << 16;
    return __builtin_bit_cast(float, w);
}

// async global->LDS, 16B per lane; lds dest must be wave-uniform base.
static __device__ __forceinline__ void gld16(const void* g, void* l) {
    __builtin_amdgcn_global_load_lds(
        (const __attribute__((address_space(1))) unsigned int*)g,
        (__attribute__((address_space(3))) unsigned int*)l, 16, 0, 0);
}

// Fragment layouts (16-row tile = 1024 bf16):
//   qf/kf[tile][h(2)][lane(64)][e(8)]: M[tile*16 + (lane&15)][h*32 + (lane>>4)*8 + e]
//   vf[tile][t(4)][lane(64)][e(4)]:  V[tile*16 + (lane>>4)*4 + e][t*16 + (lane&15)]
//   rl[row] = 1/sum_j exp2(s'_row,j)  (f32, 16384 entries)
// K is pre-scaled by log2(e) (weights+bias) so exp(s) == exp2(s').

// ---------------------------------------------------------------------------
// K1: QKV projection with fused weight prep (unchanged from R5/R6).
// ---------------------------------------------------------------------------
__global__ __launch_bounds__(256) void proj_qkv(
    const float* __restrict__ x,
    const float* __restrict__ dwq, const float* __restrict__ pwq,
    const float* __restrict__ dwk, const float* __restrict__ pwk,
    const float* __restrict__ dwv, const float* __restrict__ pwv,
    const float* __restrict__ bqp, const float* __restrict__ bkp,
    const float* __restrict__ bvp,
    __hip_bfloat16* __restrict__ qf, __hip_bfloat16* __restrict__ kf,
    __hip_bfloat16* __restrict__ vf)
{
    __shared__ __hip_bfloat16 wle[16384];   // 32 KB panel [d=64][c=256]
    int b = blockIdx.x;          // 768 blocks
    int p = b >> 8;              // 0=q 1=k 2=v
    int tg = b & 255;
    int tid = threadIdx.x;

    const float* dw = (p == 0) ? dwq : ((p == 1) ? dwk : dwv);
    const float* pw = (p == 0) ? pwq : ((p == 1) ? pwk : pwv);
    float scale = (p == 1) ? LOG2E : 1.0f;

    {
        float dwc = dw[tid];     // c = tid for every fill iteration
#pragma unroll
        for (int k = 0; k < 64; k++) {
            int idx = (k * 256 + tid) ^ ((k & 7) << 3);
            wle[idx] = __float2bfloat16(dwc * pw[tid * 64 + k] * scale);
        }
    }
    __syncthreads();

    int wv = tid >> 6;
    int wid = tg * 4 + wv;       // tile 0..1023
    int lane = tid & 63;
    int l15 = lane & 15, quad = lane >> 4;

    floatx4 acc[4];
#pragma unroll
    for (int t = 0; t < 4; t++) acc[t] = (floatx4){0.f, 0.f, 0.f, 0.f};

    const float* xrow = x + (wid * 16 + l15) * 256 + quad * 8;
#pragma unroll
    for (int ks = 0; ks < 8; ks++) {
        floatx4 xa = *reinterpret_cast<const floatx4*>(xrow + ks * 32);
        floatx4 xb = *reinterpret_cast<const floatx4*>(xrow + ks * 32 + 4);
        bf16x8 a = cvt8(xa, xb);
#pragma unroll
        for (int t = 0; t < 4; t++) {
            int j0 = ((t * 16 + l15) * 256 + ks * 32 + quad * 8) ^ ((l15 & 7) << 3);
            bf16x8 bfr = *reinterpret_cast<const bf16x8*>(&wle[j0]);
            acc[t] = MFMA16(a, bfr, acc[t]);
        }
    }
    if (p < 2) {
        __hip_bfloat16* dst = (p == 0) ? qf : kf;
        const float* bias = (p == 0) ? bqp : bkp;
        float bscale = (p == 1) ? LOG2E : 1.0f;
#pragma unroll
        for (int t = 0; t < 4; t++) {
            float bsv = bias[t * 16 + l15] * bscale;
            int off0 = wid * 1024 + (t >> 1) * 512 +
                       (((((t & 1) << 1) | (l15 >> 3)) * 16 + quad * 4) * 8) + (l15 & 7);
#pragma unroll
            for (int r = 0; r < 4; r++)
                dst[off0 + r * 8] = __float2bfloat16(acc[t][r] + bsv);
        }
    } else {
#pragma unroll
        for (int t = 0; t < 4; t++) {
            float bsv = bvp[t * 16 + l15];
            us4 pk;
#pragma unroll
            for (int r = 0; r < 4; r++) pk[r] = f2bfbits(acc[t][r] + bsv);
            *reinterpret_cast<us4*>(vf + (wid * 4 + t) * 256 + lane * 4) = pk;
        }
    }
}

// ---------------------------------------------------------------------------
// K2: row-sum reciprocals. R6-measured shape restored (R7 lesson: 1 wave/SIMD
// collapsed this trans-heavy kernel; it needs >=4 waves/SIMD more than it
// needs halved Q traffic). 512 blocks x 512 thr; block = 2 i-tiles, 8 waves
// split j (32 j-tiles each), depth-2 Q pipeline. Output rl only (no vfs).
// ---------------------------------------------------------------------------
#define P1STEP(B0, B1, B2, B3) do {                                        \
    floatx4 z = (floatx4){0.f, 0.f, 0.f, 0.f};                             \
    floatx4 sA0 = MFMA16(a1, (B1), MFMA16(a0, (B0), z));                   \
    floatx4 sA1 = MFMA16(a1, (B3), MFMA16(a0, (B2), z));                   \
    floatx4 sB0 = MFMA16(a3, (B1), MFMA16(a2, (B0), z));                   \
    floatx4 sB1 = MFMA16(a3, (B3), MFMA16(a2, (B2), z));                   \
    _Pragma("unroll")                                                      \
    for (int r = 0; r < 4; r++) {                                          \
        lsA[r] += EXP2F(sA0[r]) + EXP2F(sA1[r]);                           \
        lsB[r] += EXP2F(sB0[r]) + EXP2F(sB1[r]);                           \
    }                                                                      \
} while (0)

__global__ __launch_bounds__(512) void pass1_rl(
    const __hip_bfloat16* __restrict__ qf, const __hip_bfloat16* __restrict__ kf,
    float* __restrict__ rl)
{
    int itg0 = blockIdx.x * 2;            // i-tiles itg0, itg0+1 (same n)
    int n = itg0 >> 8;
    int jw = threadIdx.x >> 6;            // 0..7
    int lane = threadIdx.x & 63;
    int l15 = lane & 15, quad = lane >> 4;

    const __hip_bfloat16* kp = kf + itg0 * 1024 + lane * 8;
    bf16x8 a0 = load_bf8(kp);
    bf16x8 a1 = load_bf8(kp + 512);
    bf16x8 a2 = load_bf8(kp + 1024);
    bf16x8 a3 = load_bf8(kp + 1536);

    floatx4 lsA = (floatx4){0.f, 0.f, 0.f, 0.f};
    floatx4 lsB = (floatx4){0.f, 0.f, 0.f, 0.f};
    const __hip_bfloat16* qp0 = qf + (n * 256 + jw * 32) * 1024 + lane * 8;

    // stage 0 = iter it, stage 1 = iter it+1 (each iter covers 2 j-tiles)
    bf16x8 s0b0 = load_bf8(qp0);
    bf16x8 s0b1 = load_bf8(qp0 + 512);
    bf16x8 s0b2 = load_bf8(qp0 + 1024);
    bf16x8 s0b3 = load_bf8(qp0 + 1536);
    bf16x8 s1b0 = load_bf8(qp0 + 2048);
    bf16x8 s1b1 = load_bf8(qp0 + 2560);
    bf16x8 s1b2 = load_bf8(qp0 + 3072);
    bf16x8 s1b3 = load_bf8(qp0 + 3584);

    for (int it = 0; it < 16; it += 2) {
        bf16x8 n0 = load_bf8(qp0 + 4096);
        bf16x8 n1 = load_bf8(qp0 + 4608);
        bf16x8 n2 = load_bf8(qp0 + 5120);
        bf16x8 n3 = load_bf8(qp0 + 5632);
        P1STEP(s0b0, s0b1, s0b2, s0b3);
        s0b0 = n0; s0b1 = n1; s0b2 = n2; s0b3 = n3;
        bf16x8 m0 = load_bf8(qp0 + 6144);
        bf16x8 m1 = load_bf8(qp0 + 6656);
        bf16x8 m2 = load_bf8(qp0 + 7168);
        bf16x8 m3 = load_bf8(qp0 + 7680);
        P1STEP(s1b0, s1b1, s1b2, s1b3);
        s1b0 = m0; s1b1 = m1; s1b2 = m2; s1b3 = m3;
        qp0 += 4096;
    }
#pragma unroll
    for (int m = 1; m < 16; m <<= 1) {
#pragma unroll
        for (int r = 0; r < 4; r++) {
            lsA[r] += __shfl_xor(lsA[r], m, 64);
            lsB[r] += __shfl_xor(lsB[r], m, 64);
        }
    }
    __shared__ float red[8][32];
    if (l15 == 0) {
#pragma unroll
        for (int r = 0; r < 4; r++) {
            red[jw][quad * 4 + r] = lsA[r];
            red[jw][16 + quad * 4 + r] = lsB[r];
        }
    }
    __syncthreads();
    if (threadIdx.x < 32) {
        float tot = 0.f;
#pragma unroll
        for (int w = 0; w < 8; w++) tot += red[w][threadIdx.x];
        rl[itg0 * 16 + threadIdx.x] = 1.0f / tot;   // rows of tiles itg0,itg0+1
    }
}

// ---------------------------------------------------------------------------
// K3: attT partials (unchanged from R7). LDS-staged raw K/V shared by 8
// waves; P scaled by rl_i before bf16 pack. 256 blocks x 512 thr.
// ---------------------------------------------------------------------------
#define P2STEP(KA, KB, V0, V1, V2, V3, RLQ) do {                               \
    floatx4 z = (floatx4){0.f, 0.f, 0.f, 0.f};                                 \
    floatx4 s0 = MFMA16((KB), bq0b, MFMA16((KA), bq0a, z));                    \
    floatx4 s1 = MFMA16((KB), bq1b, MFMA16((KA), bq1a, z));                    \
    floatx4 s2 = MFMA16((KB), bq2b, MFMA16((KA), bq2a, z));                    \
    floatx4 s3 = MFMA16((KB), bq3b, MFMA16((KA), bq3a, z));                    \
    s16x4 p0 = pack4(EXP2F(s0[0]) * (RLQ)[0], EXP2F(s0[1]) * (RLQ)[1],         \
                     EXP2F(s0[2]) * (RLQ)[2], EXP2F(s0[3]) * (RLQ)[3]);        \
    s16x4 p1 = pack4(EXP2F(s1[0]) * (RLQ)[0], EXP2F(s1[1]) * (RLQ)[1],         \
                     EXP2F(s1[2]) * (RLQ)[2], EXP2F(s1[3]) * (RLQ)[3]);        \
    s16x4 p2 = pack4(EXP2F(s2[0]) * (RLQ)[0], EXP2F(s2[1]) * (RLQ)[1],         \
                     EXP2F(s2[2]) * (RLQ)[2], EXP2F(s2[3]) * (RLQ)[3]);        \
    s16x4 p3 = pack4(EXP2F(s3[0]) * (RLQ)[0], EXP2F(s3[1]) * (RLQ)[1],         \
                     EXP2F(s3[2]) * (RLQ)[2], EXP2F(s3[3]) * (RLQ)[3]);        \
    acc0[0] = MFMA1K(p0, (V0), acc0[0]);                                       \
    acc1[0] = MFMA1K(p1, (V0), acc1[0]);                                       \
    acc2[0] = MFMA1K(p2, (V0), acc2[0]);                                       \
    acc3[0] = MFMA1K(p3, (V0), acc3[0]);                                       \
    acc0[1] = MFMA1K(p0, (V1), acc0[1]);                                       \
    acc1[1] = MFMA1K(p1, (V1), acc1[1]);                                       \
    acc2[1] = MFMA1K(p2, (V1), acc2[1]);                                       \
    acc3[1] = MFMA1K(p3, (V1), acc3[1]);                                       \
    acc0[2] = MFMA1K(p0, (V2), acc0[2]);                                       \
    acc1[2] = MFMA1K(p1, (V2), acc1[2]);                                       \
    acc2[2] = MFMA1K(p2, (V2), acc2[2]);                                       \
    acc3[2] = MFMA1K(p3, (V2), acc3[2]);                                       \
    acc0[3] = MFMA1K(p0, (V3), acc0[3]);                                       \
    acc1[3] = MFMA1K(p1, (V3), acc1[3]);                                       \
    acc2[3] = MFMA1K(p2, (V3), acc2[3]);                                       \
    acc3[3] = MFMA1K(p3, (V3), acc3[3]);                                       \
} while (0)

__global__ __launch_bounds__(512) void pass2_att(
    const __hip_bfloat16* __restrict__ qf, const __hip_bfloat16* __restrict__ kf,
    const __hip_bfloat16* __restrict__ vf, const float* __restrict__ rl,
    unsigned short* __restrict__ attp)
{
    // double-buffered K/V: per buffer [K(t0) 2KB | K(t1) 2KB | V(t0) 2KB | V(t1) 2KB]
    __shared__ char ldsbuf[2][8192];
    __shared__ float rl_lds[512];
    int b = blockIdx.x;          // 256
    int ih = b & 7;
    int jgrp = (b >> 3) & 7;
    int n = b >> 6;
    int tid = threadIdx.x;
    int w = tid >> 6;            // 0..7
    int lane = tid & 63;
    int l15 = lane & 15, quad = lane >> 4;
    int jt0 = jgrp * 32 + w * 4; // local j-tiles jt0..jt0+3

    int it0 = n * 256 + ih * 32;

    // stage rl for the block's 512 i-rows (2 KB)
    if (tid < 128)
        *reinterpret_cast<floatx4*>(&rl_lds[tid * 4]) =
            *reinterpret_cast<const floatx4*>(&rl[it0 * 16 + tid * 4]);

    const __hip_bfloat16* qp = qf + (n * 256 + jt0) * 1024 + lane * 8;
    bf16x8 bq0a = load_bf8(qp);
    bf16x8 bq0b = load_bf8(qp + 512);
    bf16x8 bq1a = load_bf8(qp + 1024);
    bf16x8 bq1b = load_bf8(qp + 1536);
    bf16x8 bq2a = load_bf8(qp + 2048);
    bf16x8 bq2b = load_bf8(qp + 2560);
    bf16x8 bq3a = load_bf8(qp + 3072);
    bf16x8 bq3b = load_bf8(qp + 3584);

    floatx4 acc0[4], acc1[4], acc2[4], acc3[4];
#pragma unroll
    for (int t = 0; t < 4; t++) {
        acc0[t] = (floatx4){0.f, 0.f, 0.f, 0.f};
        acc1[t] = (floatx4){0.f, 0.f, 0.f, 0.f};
        acc2[t] = (floatx4){0.f, 0.f, 0.f, 0.f};
        acc3[t] = (floatx4){0.f, 0.f, 0.f, 0.f};
    }

    // staging role of this wave: w<4 -> K halves, w>=4 -> V halves
    const char* gbase = (w < 4) ? (const char*)(kf + it0 * 1024)
                                : (const char*)(vf + it0 * 1024);
    const char* gw = gbase + ((w >> 1) & 1) * 2048 + (w & 1) * 1024 + lane * 16;
    char* lw0 = &ldsbuf[0][w * 1024];
    char* lw1 = &ldsbuf[1][w * 1024];

    // prologue: stage phase 0 (tiles 0,1) into buf 0
    gld16(gw, lw0);
    __syncthreads();

    int cur = 0;
    for (int ph = 0; ph < 16; ph++) {
        if (ph < 15)
            gld16(gw + (ph + 1) * 4096, cur ? lw0 : lw1);
        const char* base = ldsbuf[cur];
#pragma unroll
        for (int t = 0; t < 2; t++) {
            bf16x8 a0 = *reinterpret_cast<const bf16x8*>(base + t * 2048 + lane * 16);
            bf16x8 a1 = *reinterpret_cast<const bf16x8*>(base + t * 2048 + 1024 + lane * 16);
            const char* vb = base + 4096 + t * 2048 + lane * 8;
            s16x4 v0 = *reinterpret_cast<const s16x4*>(vb);
            s16x4 v1 = *reinterpret_cast<const s16x4*>(vb + 512);
            s16x4 v2 = *reinterpret_cast<const s16x4*>(vb + 1024);
            s16x4 v3 = *reinterpret_cast<const s16x4*>(vb + 1536);
            floatx4 rlq = *reinterpret_cast<const floatx4*>(
                &rl_lds[(ph * 2 + t) * 16 + quad * 4]);
            P2STEP(a0, a1, v0, v1, v2, v3, rlq);
        }
        __syncthreads();   // drains staging vmcnt + all reads of buf done
        cur ^= 1;
    }
    unsigned short* op0 = attp + ih * 1048576;
#pragma unroll
    for (int t = 0; t < 4; t++) {
        s16x4 k0 = pack4(acc0[t][0], acc0[t][1], acc0[t][2], acc0[t][3]);
        s16x4 k1 = pack4(acc1[t][0], acc1[t][1], acc1[t][2], acc1[t][3]);
        s16x4 k2 = pack4(acc2[t][0], acc2[t][1], acc2[t][2], acc2[t][3]);
        s16x4 k3 = pack4(acc3[t][0], acc3[t][1], acc3[t][2], acc3[t][3]);
        unsigned short* op = op0 + (n * 64 + t * 16 + l15) * 4096 + jt0 * 16 + quad * 4;
        *reinterpret_cast<s16x4*>(op) = k0;
        *reinterpret_cast<s16x4*>(op + 16) = k1;
        *reinterpret_cast<s16x4*>(op + 32) = k2;
        *reinterpret_cast<s16x4*>(op + 48) = k3;
    }
}

// ---------------------------------------------------------------------------
// K4: final sepconv + residual, summing NPART bf16 i-partials.
// Partial reduction uses paired dword loads (2 jj per thread).
// ---------------------------------------------------------------------------
template<int NPART>
__global__ __launch_bounds__(256) void final_out(
    const unsigned short* __restrict__ attp, const float* __restrict__ gco,
    const float* __restrict__ dwa, const float* __restrict__ pwa,
    const float* __restrict__ ba, float* __restrict__ out)
{
    int b = blockIdx.x;       // 2048 blocks
    int n = b >> 9;
    int hh = (b >> 3) & 63;
    int w0 = (b & 7) << 3;
    __shared__ float g[512];
    int tid = threadIdx.x;
    const unsigned short* ap = attp + (n * 64 + hh) * 4096 + w0 * 64;
    {
        int jj0 = tid * 2;    // 256 threads x 2 = 512
        float v0 = 0.f, v1 = 0.f;
#pragma unroll
        for (int ph = 0; ph < NPART; ph++) {
            unsigned int u = *reinterpret_cast<const unsigned int*>(ap + ph * 1048576 + jj0);
            v0 += bf2f((unsigned short)(u & 0xffffu));
            v1 += bf2f((unsigned short)(u >> 16));
        }
        g[jj0] = v0 * dwa[jj0 & 63];
        g[jj0 + 1] = v1 * dwa[(jj0 + 1) & 63];
    }
    __syncthreads();
    float acc[8];
#pragma unroll
    for (int w = 0; w < 8; w++) acc[w] = 0.f;
    for (int cc = 0; cc < 64; cc++) {
        float p = pwa[cc * 256 + tid];
#pragma unroll
        for (int w = 0; w < 8; w++) acc[w] += g[w * 64 + cc] * p;
    }
    float bb = ba[tid];
#pragma unroll
    for (int w = 0; w < 8; w++) {
        int pos = (n * 64 + hh) * 64 + w0 + w;
        float gv = gco[pos * 256 + tid];
        out[pos * 256 + tid] = gv * (acc[w] + bb) + gv;
    }
}

// ---------------------------------------------------------------------------
extern "C" void kernel_launch(void* const* d_in, const int* in_sizes, int n_in,
                              void* d_out, int out_size, void* d_ws, size_t ws_size,
                              hipStream_t stream) {
    const float* x   = (const float*)d_in[0];
    const float* gco = (const float*)d_in[1];
    const float* dwq = (const float*)d_in[2];
    const float* pwq = (const float*)d_in[3];
    const float* bq  = (const float*)d_in[4];
    const float* dwk = (const float*)d_in[5];
    const float* pwk = (const float*)d_in[6];
    const float* bk  = (const float*)d_in[7];
    const float* dwv = (const float*)d_in[8];
    const float* pwv = (const float*)d_in[9];
    const float* bv  = (const float*)d_in[10];
    const float* dwa = (const float*)d_in[11];
    const float* pwa = (const float*)d_in[12];
    const float* ba  = (const float*)d_in[13];
    float* out = (float*)d_out;

    char* ws = (char*)d_ws;
    __hip_bfloat16* qf  = (__hip_bfloat16*)(ws + 98304);          // 2 MB
    __hip_bfloat16* kf  = (__hip_bfloat16*)(ws + 2195456);        // 2 MB
    __hip_bfloat16* vf  = (__hip_bfloat16*)(ws + 4292608);        // 2 MB
    float*          rlb = (float*)(ws + 6389760);                 // 64 KB
    unsigned short* attp = (unsigned short*)(ws + 8486912);       // 8 x 2 MB bf16

    proj_qkv<<<768, 256, 0, stream>>>(x, dwq, pwq, dwk, pwk, dwv, pwv,
                                      bq, bk, bv, qf, kf, vf);
    pass1_rl<<<512, 512, 0, stream>>>(qf, kf, rlb);
    pass2_att<<<256, 512, 0, stream>>>(qf, kf, vf, rlb, attp);
    final_out<8><<<2048, 256, 0, stream>>>(attp, gco, dwa, pwa, ba, out);
}

// Round 9
// 164.656 us; speedup vs baseline: 1.1205x; 1.0157x over previous
//
#include <hip/hip_runtime.h>
#include <hip/hip_bf16.h>

typedef __attribute__((ext_vector_type(8))) __bf16 bf16x8;
typedef __attribute__((ext_vector_type(2))) __bf16 bf16x2;
typedef __attribute__((ext_vector_type(4))) float floatx4;
typedef __attribute__((ext_vector_type(4))) unsigned short us4;
typedef __attribute__((ext_vector_type(8))) unsigned short us8;
typedef __attribute__((ext_vector_type(4))) short s16x4;
typedef __attribute__((ext_vector_type(2))) unsigned int uint2v;
typedef __attribute__((ext_vector_type(4))) unsigned int uint4v;

#define MFMA16(A, B, C) __builtin_amdgcn_mfma_f32_16x16x32_bf16((A), (B), (C), 0, 0, 0)
#define MFMA1K(A, B, C) __builtin_amdgcn_mfma_f32_16x16x16bf16_1k((A), (B), (C), 0, 0, 0)

#define LOG2E 1.44269504088896340736f

#if __has_builtin(__builtin_amdgcn_exp2f)
#define EXP2F(x) __builtin_amdgcn_exp2f(x)
#else
#define EXP2F(x) exp2f(x)
#endif

static __device__ __forceinline__ unsigned short f2bfbits(float f) {
    __hip_bfloat16 h = __float2bfloat16(f);
    union { __hip_bfloat16 h; unsigned short u; } cv;
    cv.h = h;
    return cv.u;
}
// fast bf16 RNE (finite moderate values only)
static __device__ __forceinline__ unsigned int rne32(float f) {
    unsigned int u = __builtin_bit_cast(unsigned int, f);
    return u + 0x7fffu + ((u >> 16) & 1u);
}
static __device__ __forceinline__ unsigned short rne16(float f) {
    return (unsigned short)(rne32(f) >> 16);
}

#if __has_builtin(__builtin_amdgcn_cvt_pk_bf16_f32)
static __device__ __forceinline__ s16x4 pack4(float e0, float e1, float e2, float e3) {
    bf16x2 lo = __builtin_amdgcn_cvt_pk_bf16_f32(e0, e1);
    bf16x2 hi = __builtin_amdgcn_cvt_pk_bf16_f32(e2, e3);
    uint2v u = {__builtin_bit_cast(unsigned int, lo), __builtin_bit_cast(unsigned int, hi)};
    return __builtin_bit_cast(s16x4, u);
}
static __device__ __forceinline__ bf16x8 cvt8(floatx4 a, floatx4 b) {
    bf16x2 p0 = __builtin_amdgcn_cvt_pk_bf16_f32(a[0], a[1]);
    bf16x2 p1 = __builtin_amdgcn_cvt_pk_bf16_f32(a[2], a[3]);
    bf16x2 p2 = __builtin_amdgcn_cvt_pk_bf16_f32(b[0], b[1]);
    bf16x2 p3 = __builtin_amdgcn_cvt_pk_bf16_f32(b[2], b[3]);
    uint4v u = {__builtin_bit_cast(unsigned int, p0), __builtin_bit_cast(unsigned int, p1),
                __builtin_bit_cast(unsigned int, p2), __builtin_bit_cast(unsigned int, p3)};
    return __builtin_bit_cast(bf16x8, u);
}
#else
static __device__ __forceinline__ s16x4 pack4(float e0, float e1, float e2, float e3) {
    unsigned int pa = __builtin_amdgcn_perm(rne32(e1), rne32(e0), 0x07060302u);
    unsigned int pb = __builtin_amdgcn_perm(rne32(e3), rne32(e2), 0x07060302u);
    uint2v u = {pa, pb};
    return __builtin_bit_cast(s16x4, u);
}
static __device__ __forceinline__ bf16x8 cvt8(floatx4 a, floatx4 b) {
    us8 u;
#pragma unroll
    for (int i = 0; i < 4; i++) { u[i] = rne16(a[i]); u[4 + i] = rne16(b[i]); }
    return __builtin_bit_cast(bf16x8, u);
}
#endif

static __device__ __forceinline__ bf16x8 load_bf8(const __hip_bfloat16* p) {
    return *reinterpret_cast<const bf16x8*>(p);
}
static __device__ __forceinline__ float bf2f(unsigned short u) {
    unsigned int w = ((unsigned int)u) << 16;
    return __builtin_bit_cast(float, w);
}

// async global->LDS, 16B per lane; lds dest must be wave-uniform base.
static __device__ __forceinline__ void gld16(const void* g, void* l) {
    __builtin_amdgcn_global_load_lds(
        (const __attribute__((address_space(1))) unsigned int*)g,
        (__attribute__((address_space(3))) unsigned int*)l, 16, 0, 0);
}

// Fragment layouts (16-row tile = 1024 bf16):
//   qf/kf[tile][h(2)][lane(64)][e(8)]: M[tile*16 + (lane&15)][h*32 + (lane>>4)*8 + e]
//   vf[tile][t(4)][lane(64)][e(4)]:  V[tile*16 + (lane>>4)*4 + e][t*16 + (lane&15)]
//   rl[row] = 1/sum_j exp2(s'_row,j)  (f32, 16384 entries)
// K is pre-scaled by log2(e) (weights+bias) so exp(s) == exp2(s').

// ---------------------------------------------------------------------------
// K1: QKV projection with fused weight prep (unchanged from R5/R6).
// ---------------------------------------------------------------------------
__global__ __launch_bounds__(256) void proj_qkv(
    const float* __restrict__ x,
    const float* __restrict__ dwq, const float* __restrict__ pwq,
    const float* __restrict__ dwk, const float* __restrict__ pwk,
    const float* __restrict__ dwv, const float* __restrict__ pwv,
    const float* __restrict__ bqp, const float* __restrict__ bkp,
    const float* __restrict__ bvp,
    __hip_bfloat16* __restrict__ qf, __hip_bfloat16* __restrict__ kf,
    __hip_bfloat16* __restrict__ vf)
{
    __shared__ __hip_bfloat16 wle[16384];   // 32 KB panel [d=64][c=256]
    int b = blockIdx.x;          // 768 blocks
    int p = b >> 8;              // 0=q 1=k 2=v
    int tg = b & 255;
    int tid = threadIdx.x;

    const float* dw = (p == 0) ? dwq : ((p == 1) ? dwk : dwv);
    const float* pw = (p == 0) ? pwq : ((p == 1) ? pwk : pwv);
    float scale = (p == 1) ? LOG2E : 1.0f;

    {
        float dwc = dw[tid];     // c = tid for every fill iteration
#pragma unroll
        for (int k = 0; k < 64; k++) {
            int idx = (k * 256 + tid) ^ ((k & 7) << 3);
            wle[idx] = __float2bfloat16(dwc * pw[tid * 64 + k] * scale);
        }
    }
    __syncthreads();

    int wv = tid >> 6;
    int wid = tg * 4 + wv;       // tile 0..1023
    int lane = tid & 63;
    int l15 = lane & 15, quad = lane >> 4;

    floatx4 acc[4];
#pragma unroll
    for (int t = 0; t < 4; t++) acc[t] = (floatx4){0.f, 0.f, 0.f, 0.f};

    const float* xrow = x + (wid * 16 + l15) * 256 + quad * 8;
#pragma unroll
    for (int ks = 0; ks < 8; ks++) {
        floatx4 xa = *reinterpret_cast<const floatx4*>(xrow + ks * 32);
        floatx4 xb = *reinterpret_cast<const floatx4*>(xrow + ks * 32 + 4);
        bf16x8 a = cvt8(xa, xb);
#pragma unroll
        for (int t = 0; t < 4; t++) {
            int j0 = ((t * 16 + l15) * 256 + ks * 32 + quad * 8) ^ ((l15 & 7) << 3);
            bf16x8 bfr = *reinterpret_cast<const bf16x8*>(&wle[j0]);
            acc[t] = MFMA16(a, bfr, acc[t]);
        }
    }
    if (p < 2) {
        __hip_bfloat16* dst = (p == 0) ? qf : kf;
        const float* bias = (p == 0) ? bqp : bkp;
        float bscale = (p == 1) ? LOG2E : 1.0f;
#pragma unroll
        for (int t = 0; t < 4; t++) {
            float bsv = bias[t * 16 + l15] * bscale;
            int off0 = wid * 1024 + (t >> 1) * 512 +
                       (((((t & 1) << 1) | (l15 >> 3)) * 16 + quad * 4) * 8) + (l15 & 7);
#pragma unroll
            for (int r = 0; r < 4; r++)
                dst[off0 + r * 8] = __float2bfloat16(acc[t][r] + bsv);
        }
    } else {
#pragma unroll
        for (int t = 0; t < 4; t++) {
            float bsv = bvp[t * 16 + l15];
            us4 pk;
#pragma unroll
            for (int r = 0; r < 4; r++) pk[r] = f2bfbits(acc[t][r] + bsv);
            *reinterpret_cast<us4*>(vf + (wid * 4 + t) * 256 + lane * 4) = pk;
        }
    }
}

// ---------------------------------------------------------------------------
// K2: row-sum reciprocals (unchanged from R8: R6-proven shape).
// 512 blocks x 512 thr; block = 2 i-tiles, 8 waves split j, depth-2 pipeline.
// ---------------------------------------------------------------------------
#define P1STEP(B0, B1, B2, B3) do {                                        \
    floatx4 z = (floatx4){0.f, 0.f, 0.f, 0.f};                             \
    floatx4 sA0 = MFMA16(a1, (B1), MFMA16(a0, (B0), z));                   \
    floatx4 sA1 = MFMA16(a1, (B3), MFMA16(a0, (B2), z));                   \
    floatx4 sB0 = MFMA16(a3, (B1), MFMA16(a2, (B0), z));                   \
    floatx4 sB1 = MFMA16(a3, (B3), MFMA16(a2, (B2), z));                   \
    _Pragma("unroll")                                                      \
    for (int r = 0; r < 4; r++) {                                          \
        lsA[r] += EXP2F(sA0[r]) + EXP2F(sA1[r]);                           \
        lsB[r] += EXP2F(sB0[r]) + EXP2F(sB1[r]);                           \
    }                                                                      \
} while (0)

__global__ __launch_bounds__(512) void pass1_rl(
    const __hip_bfloat16* __restrict__ qf, const __hip_bfloat16* __restrict__ kf,
    float* __restrict__ rl)
{
    int itg0 = blockIdx.x * 2;            // i-tiles itg0, itg0+1 (same n)
    int n = itg0 >> 8;
    int jw = threadIdx.x >> 6;            // 0..7
    int lane = threadIdx.x & 63;
    int l15 = lane & 15, quad = lane >> 4;

    const __hip_bfloat16* kp = kf + itg0 * 1024 + lane * 8;
    bf16x8 a0 = load_bf8(kp);
    bf16x8 a1 = load_bf8(kp + 512);
    bf16x8 a2 = load_bf8(kp + 1024);
    bf16x8 a3 = load_bf8(kp + 1536);

    floatx4 lsA = (floatx4){0.f, 0.f, 0.f, 0.f};
    floatx4 lsB = (floatx4){0.f, 0.f, 0.f, 0.f};
    const __hip_bfloat16* qp0 = qf + (n * 256 + jw * 32) * 1024 + lane * 8;

    // stage 0 = iter it, stage 1 = iter it+1 (each iter covers 2 j-tiles)
    bf16x8 s0b0 = load_bf8(qp0);
    bf16x8 s0b1 = load_bf8(qp0 + 512);
    bf16x8 s0b2 = load_bf8(qp0 + 1024);
    bf16x8 s0b3 = load_bf8(qp0 + 1536);
    bf16x8 s1b0 = load_bf8(qp0 + 2048);
    bf16x8 s1b1 = load_bf8(qp0 + 2560);
    bf16x8 s1b2 = load_bf8(qp0 + 3072);
    bf16x8 s1b3 = load_bf8(qp0 + 3584);

    for (int it = 0; it < 16; it += 2) {
        bf16x8 n0 = load_bf8(qp0 + 4096);
        bf16x8 n1 = load_bf8(qp0 + 4608);
        bf16x8 n2 = load_bf8(qp0 + 5120);
        bf16x8 n3 = load_bf8(qp0 + 5632);
        P1STEP(s0b0, s0b1, s0b2, s0b3);
        s0b0 = n0; s0b1 = n1; s0b2 = n2; s0b3 = n3;
        bf16x8 m0 = load_bf8(qp0 + 6144);
        bf16x8 m1 = load_bf8(qp0 + 6656);
        bf16x8 m2 = load_bf8(qp0 + 7168);
        bf16x8 m3 = load_bf8(qp0 + 7680);
        P1STEP(s1b0, s1b1, s1b2, s1b3);
        s1b0 = m0; s1b1 = m1; s1b2 = m2; s1b3 = m3;
        qp0 += 4096;
    }
#pragma unroll
    for (int m = 1; m < 16; m <<= 1) {
#pragma unroll
        for (int r = 0; r < 4; r++) {
            lsA[r] += __shfl_xor(lsA[r], m, 64);
            lsB[r] += __shfl_xor(lsB[r], m, 64);
        }
    }
    __shared__ float red[8][32];
    if (l15 == 0) {
#pragma unroll
        for (int r = 0; r < 4; r++) {
            red[jw][quad * 4 + r] = lsA[r];
            red[jw][16 + quad * 4 + r] = lsB[r];
        }
    }
    __syncthreads();
    if (threadIdx.x < 32) {
        float tot = 0.f;
#pragma unroll
        for (int w = 0; w < 8; w++) tot += red[w][threadIdx.x];
        rl[itg0 * 16 + threadIdx.x] = 1.0f / tot;   // rows of tiles itg0,itg0+1
    }
}

// ---------------------------------------------------------------------------
// K3: attT partials. R9 change: 2 blocks/CU for barrier-drain overlap.
// At 256 blocks (1/CU) every __syncthreads serialized compute behind the
// staging load's vmcnt(0) drain with nothing else to run. Halving per-wave
// j-tiles (4->2: acc 64->32, bq 32->16 VGPR, peak ~100 < 128) lets TWO
// 512-thr blocks co-reside: block B computes through block A's drain.
// Grid = n(4) x jgrp(16) x ih(8) = 512 blocks; LDS 18.5 KB x 2 = 37 KB/CU.
// ---------------------------------------------------------------------------
#define P2STEP(KA, KB, V0, V1, V2, V3, RLQ) do {                               \
    floatx4 z = (floatx4){0.f, 0.f, 0.f, 0.f};                                 \
    floatx4 s0 = MFMA16((KB), bq0b, MFMA16((KA), bq0a, z));                    \
    floatx4 s1 = MFMA16((KB), bq1b, MFMA16((KA), bq1a, z));                    \
    s16x4 p0 = pack4(EXP2F(s0[0]) * (RLQ)[0], EXP2F(s0[1]) * (RLQ)[1],         \
                     EXP2F(s0[2]) * (RLQ)[2], EXP2F(s0[3]) * (RLQ)[3]);        \
    s16x4 p1 = pack4(EXP2F(s1[0]) * (RLQ)[0], EXP2F(s1[1]) * (RLQ)[1],         \
                     EXP2F(s1[2]) * (RLQ)[2], EXP2F(s1[3]) * (RLQ)[3]);        \
    acc0[0] = MFMA1K(p0, (V0), acc0[0]);                                       \
    acc1[0] = MFMA1K(p1, (V0), acc1[0]);                                       \
    acc0[1] = MFMA1K(p0, (V1), acc0[1]);                                       \
    acc1[1] = MFMA1K(p1, (V1), acc1[1]);                                       \
    acc0[2] = MFMA1K(p0, (V2), acc0[2]);                                       \
    acc1[2] = MFMA1K(p1, (V2), acc1[2]);                                       \
    acc0[3] = MFMA1K(p0, (V3), acc0[3]);                                       \
    acc1[3] = MFMA1K(p1, (V3), acc1[3]);                                       \
} while (0)

__global__ __launch_bounds__(512) void pass2_att(
    const __hip_bfloat16* __restrict__ qf, const __hip_bfloat16* __restrict__ kf,
    const __hip_bfloat16* __restrict__ vf, const float* __restrict__ rl,
    unsigned short* __restrict__ attp)
{
    // double-buffered K/V: per buffer [K(t0) 2KB | K(t1) 2KB | V(t0) 2KB | V(t1) 2KB]
    __shared__ char ldsbuf[2][8192];
    __shared__ float rl_lds[512];
    int b = blockIdx.x;          // 512
    int ih = b & 7;
    int jgrp = (b >> 3) & 15;
    int n = b >> 7;
    int tid = threadIdx.x;
    int w = tid >> 6;            // 0..7
    int lane = tid & 63;
    int l15 = lane & 15, quad = lane >> 4;
    int jt0 = jgrp * 16 + w * 2; // local j-tiles jt0, jt0+1

    int it0 = n * 256 + ih * 32;

    // stage rl for the block's 512 i-rows (2 KB)
    if (tid < 128)
        *reinterpret_cast<floatx4*>(&rl_lds[tid * 4]) =
            *reinterpret_cast<const floatx4*>(&rl[it0 * 16 + tid * 4]);

    const __hip_bfloat16* qp = qf + (n * 256 + jt0) * 1024 + lane * 8;
    bf16x8 bq0a = load_bf8(qp);
    bf16x8 bq0b = load_bf8(qp + 512);
    bf16x8 bq1a = load_bf8(qp + 1024);
    bf16x8 bq1b = load_bf8(qp + 1536);

    floatx4 acc0[4], acc1[4];
#pragma unroll
    for (int t = 0; t < 4; t++) {
        acc0[t] = (floatx4){0.f, 0.f, 0.f, 0.f};
        acc1[t] = (floatx4){0.f, 0.f, 0.f, 0.f};
    }

    // staging role of this wave: w<4 -> K halves, w>=4 -> V halves
    const char* gbase = (w < 4) ? (const char*)(kf + it0 * 1024)
                                : (const char*)(vf + it0 * 1024);
    const char* gw = gbase + ((w >> 1) & 1) * 2048 + (w & 1) * 1024 + lane * 16;
    char* lw0 = &ldsbuf[0][w * 1024];
    char* lw1 = &ldsbuf[1][w * 1024];

    // prologue: stage phase 0 (tiles 0,1) into buf 0
    gld16(gw, lw0);
    __syncthreads();

    int cur = 0;
    for (int ph = 0; ph < 16; ph++) {
        if (ph < 15)
            gld16(gw + (ph + 1) * 4096, cur ? lw0 : lw1);
        const char* base = ldsbuf[cur];
#pragma unroll
        for (int t = 0; t < 2; t++) {
            bf16x8 a0 = *reinterpret_cast<const bf16x8*>(base + t * 2048 + lane * 16);
            bf16x8 a1 = *reinterpret_cast<const bf16x8*>(base + t * 2048 + 1024 + lane * 16);
            const char* vb = base + 4096 + t * 2048 + lane * 8;
            s16x4 v0 = *reinterpret_cast<const s16x4*>(vb);
            s16x4 v1 = *reinterpret_cast<const s16x4*>(vb + 512);
            s16x4 v2 = *reinterpret_cast<const s16x4*>(vb + 1024);
            s16x4 v3 = *reinterpret_cast<const s16x4*>(vb + 1536);
            floatx4 rlq = *reinterpret_cast<const floatx4*>(
                &rl_lds[(ph * 2 + t) * 16 + quad * 4]);
            P2STEP(a0, a1, v0, v1, v2, v3, rlq);
        }
        __syncthreads();   // drains staging vmcnt + all reads of buf done
        cur ^= 1;
    }
    unsigned short* op0 = attp + ih * 1048576;
#pragma unroll
    for (int t = 0; t < 4; t++) {
        s16x4 k0 = pack4(acc0[t][0], acc0[t][1], acc0[t][2], acc0[t][3]);
        s16x4 k1 = pack4(acc1[t][0], acc1[t][1], acc1[t][2], acc1[t][3]);
        unsigned short* op = op0 + (n * 64 + t * 16 + l15) * 4096 + jt0 * 16 + quad * 4;
        *reinterpret_cast<s16x4*>(op) = k0;
        *reinterpret_cast<s16x4*>(op + 16) = k1;
    }
}

// ---------------------------------------------------------------------------
// K4: final sepconv + residual, summing NPART bf16 i-partials.
// Partial reduction uses paired dword loads (2 jj per thread).
// ---------------------------------------------------------------------------
template<int NPART>
__global__ __launch_bounds__(256) void final_out(
    const unsigned short* __restrict__ attp, const float* __restrict__ gco,
    const float* __restrict__ dwa, const float* __restrict__ pwa,
    const float* __restrict__ ba, float* __restrict__ out)
{
    int b = blockIdx.x;       // 2048 blocks
    int n = b >> 9;
    int hh = (b >> 3) & 63;
    int w0 = (b & 7) << 3;
    __shared__ float g[512];
    int tid = threadIdx.x;
    const unsigned short* ap = attp + (n * 64 + hh) * 4096 + w0 * 64;
    {
        int jj0 = tid * 2;    // 256 threads x 2 = 512
        float v0 = 0.f, v1 = 0.f;
#pragma unroll
        for (int ph = 0; ph < NPART; ph++) {
            unsigned int u = *reinterpret_cast<const unsigned int*>(ap + ph * 1048576 + jj0);
            v0 += bf2f((unsigned short)(u & 0xffffu));
            v1 += bf2f((unsigned short)(u >> 16));
        }
        g[jj0] = v0 * dwa[jj0 & 63];
        g[jj0 + 1] = v1 * dwa[(jj0 + 1) & 63];
    }
    __syncthreads();
    float acc[8];
#pragma unroll
    for (int w = 0; w < 8; w++) acc[w] = 0.f;
    for (int cc = 0; cc < 64; cc++) {
        float p = pwa[cc * 256 + tid];
#pragma unroll
        for (int w = 0; w < 8; w++) acc[w] += g[w * 64 + cc] * p;
    }
    float bb = ba[tid];
#pragma unroll
    for (int w = 0; w < 8; w++) {
        int pos = (n * 64 + hh) * 64 + w0 + w;
        float gv = gco[pos * 256 + tid];
        out[pos * 256 + tid] = gv * (acc[w] + bb) + gv;
    }
}

// ---------------------------------------------------------------------------
extern "C" void kernel_launch(void* const* d_in, const int* in_sizes, int n_in,
                              void* d_out, int out_size, void* d_ws, size_t ws_size,
                              hipStream_t stream) {
    const float* x   = (const float*)d_in[0];
    const float* gco = (const float*)d_in[1];
    const float* dwq = (const float*)d_in[2];
    const float* pwq = (const float*)d_in[3];
    const float* bq  = (const float*)d_in[4];
    const float* dwk = (const float*)d_in[5];
    const float* pwk = (const float*)d_in[6];
    const float* bk  = (const float*)d_in[7];
    const float* dwv = (const float*)d_in[8];
    const float* pwv = (const float*)d_in[9];
    const float* bv  = (const float*)d_in[10];
    const float* dwa = (const float*)d_in[11];
    const float* pwa = (const float*)d_in[12];
    const float* ba  = (const float*)d_in[13];
    float* out = (float*)d_out;

    char* ws = (char*)d_ws;
    __hip_bfloat16* qf  = (__hip_bfloat16*)(ws + 98304);          // 2 MB
    __hip_bfloat16* kf  = (__hip_bfloat16*)(ws + 2195456);        // 2 MB
    __hip_bfloat16* vf  = (__hip_bfloat16*)(ws + 4292608);        // 2 MB
    float*          rlb = (float*)(ws + 6389760);                 // 64 KB
    unsigned short* attp = (unsigned short*)(ws + 8486912);       // 8 x 2 MB bf16

    proj_qkv<<<768, 256, 0, stream>>>(x, dwq, pwq, dwk, pwk, dwv, pwv,
                                      bq, bk, bv, qf, kf, vf);
    pass1_rl<<<512, 512, 0, stream>>>(qf, kf, rlb);
    pass2_att<<<512, 512, 0, stream>>>(qf, kf, vf, rlb, attp);
    final_out<8><<<2048, 256, 0, stream>>>(attp, gco, dwa, pwa, ba, out);
}